// Round 4
// baseline (110.932 us; speedup 1.0000x reference)
//
#include <hip/hip_runtime.h>
#include <hip/hip_cooperative_groups.h>
#include <math.h>

#define BATCH 16384
#define NW 10
#define DEPTH 2

namespace cg = cooperative_groups;

// ============================================================================
// Single cooperative kernel, 128 blocks x 128 threads (256 waves).
//  Phase B: wave q=(blk*2+wv) handles pair (a=q>>4, b=q&15): simulates the two
//           batch-independent circuit columns u_a, u_b in registers (verified
//           k1 shuffle simulator), computes C_w[a][b] directly via butterfly.
//  grid.sync()
//  Phase C: each block gathers K (81 trig-basis terms x 10 wires) from C into
//           LDS (verified k2b transform).
//  Phase D: each thread evaluates one batch element: 81 products x 10 FMAs.
// ============================================================================

__device__ __forceinline__ void sim_column(int a, int lane,
                                           const float* ct, const float* st_,
                                           float re[16], float im[16])
{
#pragma unroll
    for (int r = 0; r < 16; ++r) { re[r] = 0.0f; im[r] = 0.0f; }
    if (lane == 0) re[a] = 1.0f;     // |a<<6>

#pragma unroll 1
    for (int d = 0; d < DEPTH; ++d) {
#pragma unroll
        for (int w = 0; w < 4; ++w) {            // RX on register wires
            const float c = ct[w], s = st_[w];
            const int m = 8 >> w;
#pragma unroll
            for (int r = 0; r < 16; ++r) {
                if (!(r & m)) {
                    const int r1 = r | m;
                    const float a0r = re[r],  a0i = im[r];
                    const float a1r = re[r1], a1i = im[r1];
                    re[r]  = c * a0r + s * a1i;
                    im[r]  = c * a0i - s * a1r;
                    re[r1] = c * a1r + s * a0i;
                    im[r1] = c * a1i - s * a0r;
                }
            }
        }
#pragma unroll
        for (int w = 4; w < 10; ++w) {           // RX on lane wires
            const float c = ct[w], s = st_[w];
            const int lm = 32 >> (w - 4);
#pragma unroll
            for (int r = 0; r < 16; ++r) {
                const float pr = __shfl_xor(re[r], lm, 64);
                const float pi = __shfl_xor(im[r], lm, 64);
                re[r] = c * re[r] + s * pi;
                im[r] = c * im[r] - s * pr;
            }
        }
        // ring CNOTs (0,1)(1,2)(2,3): register swaps
#pragma unroll
        for (int w = 0; w < 3; ++w) {
            const int cm = 8 >> w, tm = 8 >> (w + 1);
#pragma unroll
            for (int r = 0; r < 16; ++r) {
                if ((r & cm) && !(r & tm)) {
                    const int r2 = r | tm;
                    float t;
                    t = re[r]; re[r] = re[r2]; re[r2] = t;
                    t = im[r]; im[r] = im[r2]; im[r2] = t;
                }
            }
        }
        // (3,4): odd registers swap lanes across bit5
#pragma unroll
        for (int r = 0; r < 16; ++r) {
            if (r & 1) {
                re[r] = __shfl_xor(re[r], 32, 64);
                im[r] = __shfl_xor(im[r], 32, 64);
            }
        }
        // (4,5)..(8,9): lane-bit CNOTs
#pragma unroll
        for (int w = 4; w < 9; ++w) {
            const int cm = 32 >> (w - 4), tm = 32 >> (w - 3);
            const bool ctl = (lane & cm) != 0;
#pragma unroll
            for (int r = 0; r < 16; ++r) {
                const float pr = __shfl_xor(re[r], tm, 64);
                const float pi = __shfl_xor(im[r], tm, 64);
                re[r] = ctl ? pr : re[r];
                im[r] = ctl ? pi : im[r];
            }
        }
        // (9,0): lane-bit0 controlled register-bit3 swap
        {
            const bool ctl = (lane & 1) != 0;
#pragma unroll
            for (int r = 0; r < 8; ++r) {
                const float t0r = re[r], t1r = re[r + 8];
                const float t0i = im[r], t1i = im[r + 8];
                re[r]     = ctl ? t1r : t0r;
                re[r + 8] = ctl ? t0r : t1r;
                im[r]     = ctl ? t1i : t0i;
                im[r + 8] = ctl ? t0i : t1i;
            }
        }
    }
}

__global__ __launch_bounds__(128) void fused_all(const float* __restrict__ x,
                                                 const float* __restrict__ theta,
                                                 float* __restrict__ out,
                                                 float* __restrict__ Cg)
{
    const int lane = threadIdx.x & 63;
    const int wv   = threadIdx.x >> 6;           // 0..1
    const int q    = blockIdx.x * 2 + wv;        // 0..255 pair id
    const int a    = q >> 4, b = q & 15;

    // ---- phase B: pair (a,b) -> C_w[a][b] --------------------------------
    {
        float ct[NW], st_[NW];
#pragma unroll
        for (int w = 0; w < NW; ++w) {
            const float h = 0.5f * theta[w];
            ct[w] = __cosf(h); st_[w] = __sinf(h);
        }

        float ar[16], ai[16], br[16], bi[16];
        sim_column(a, lane, ct, st_, ar, ai);
        sim_column(b, lane, ct, st_, br, bi);

        const int p = (__popc(a) - __popc(b)) & 3;     // wave-uniform
        const bool odd = (p & 1) != 0;

        // per-lane partial sums: v = selected component of conj(u_a)*u_b
        float red[10];
#pragma unroll
        for (int k = 0; k < 10; ++k) red[k] = 0.0f;
#pragma unroll
        for (int r = 0; r < 16; ++r) {
            const float vr = ar[r] * br[r] + ai[r] * bi[r];  // Re
            const float vi = ar[r] * bi[r] - ai[r] * br[r];  // Im
            const float v  = odd ? vi : vr;
            red[0] += (r & 8) ? -v : v;     // wire 0 (reg bit 3)
            red[1] += (r & 4) ? -v : v;
            red[2] += (r & 2) ? -v : v;
            red[3] += (r & 1) ? -v : v;
            red[4] += v;                    // T, lane signs applied below
        }
        const float T = red[4];
        red[4] = (lane & 32) ? -T : T;      // wire 4 (lane bit 5)
        red[5] = (lane & 16) ? -T : T;
        red[6] = (lane &  8) ? -T : T;
        red[7] = (lane &  4) ? -T : T;
        red[8] = (lane &  2) ? -T : T;
        red[9] = (lane &  1) ? -T : T;

#pragma unroll
        for (int k = 0; k < 10; ++k) {
            float v = red[k];
#pragma unroll
            for (int ofs = 32; ofs >= 1; ofs >>= 1)
                v += __shfl_xor(v, ofs, 64);
            red[k] = v;
        }

        if (lane == 0) {
            // C = Re(i^p S): p=0 -> +Sr, 1 -> -Si, 2 -> -Sr, 3 -> +Si
            const float sg = (p == 1 || p == 2) ? -1.0f : 1.0f;
#pragma unroll
            for (int w = 0; w < NW; ++w)
                Cg[q * 12 + w] = sg * red[w];
        }
    }

    __threadfence();                 // make C device-visible (cross-XCD)
    cg::this_grid().sync();

    // ---- phase C: build K (81 x 10) in LDS from C ------------------------
    __shared__ float sC[256 * 12];
    __shared__ float sK[81 * 12];
    for (int i = threadIdx.x; i < 256 * 12; i += 128) sC[i] = Cg[i];
    __syncthreads();

    for (int idx = threadIdx.x; idx < 810; idx += 128) {
        const int t = idx / 10, w = idx - 10 * t;
        int d0 = t / 27, r0 = t - d0 * 27;
        int d1 = r0 / 9, r1 = r0 - d1 * 9;
        int d2 = r1 / 3, d3 = r1 - d2 * 3;
        const int d[4] = { d0, d1, d2, d3 };

        float s = 0.0f;
#pragma unroll
        for (int e = 0; e < 16; ++e) {
            int aa = 0, bb = 0; float sgn = 1.0f;
#pragma unroll
            for (int qq = 0; qq < 4; ++qq) {
                const int eq = (e >> (3 - qq)) & 1;
                int aq, bq;
                if (d[qq] == 2) { aq = eq; bq = 1 - eq; }
                else {
                    aq = eq; bq = eq;
                    if (d[qq] == 1 && eq) sgn = -sgn;
                }
                aa |= aq << (3 - qq);
                bb |= bq << (3 - qq);
            }
            s += sgn * sC[(aa * 16 + bb) * 12 + w];
        }
        sK[t * 12 + w] = s * 0.0625f;
    }
    __syncthreads();

    // ---- phase D: per-batch trig-basis evaluation ------------------------
    const int bidx = blockIdx.x * 128 + threadIdx.x;   // 0..16383
    const float4 xv = ((const float4*)x)[bidx];

    float s0, c0, s1, c1, s2, c2, s3, c3;
    __sincosf(xv.x, &s0, &c0);
    __sincosf(xv.y, &s1, &c1);
    __sincosf(xv.z, &s2, &c2);
    __sincosf(xv.w, &s3, &c3);

    const float b0[3] = { 1.0f, c0, s0 };
    const float b1[3] = { 1.0f, c1, s1 };
    const float b2[3] = { 1.0f, c2, s2 };
    const float b3[3] = { 1.0f, c3, s3 };
    float B01[9], B23[9];
#pragma unroll
    for (int i = 0; i < 3; ++i)
#pragma unroll
        for (int j = 0; j < 3; ++j) {
            B01[i * 3 + j] = b0[i] * b1[j];
            B23[i * 3 + j] = b2[i] * b3[j];
        }

    float z[NW];
#pragma unroll
    for (int w = 0; w < NW; ++w) z[w] = 0.0f;

#pragma unroll
    for (int t01 = 0; t01 < 9; ++t01) {
#pragma unroll
        for (int t23 = 0; t23 < 9; ++t23) {
            const float P = B01[t01] * B23[t23];
            const float* base = &sK[(t01 * 9 + t23) * 12];
            const float4 q0 = *(const float4*)(base + 0);
            const float4 q1 = *(const float4*)(base + 4);
            const float4 q2 = *(const float4*)(base + 8);
            z[0] = fmaf(P, q0.x, z[0]);
            z[1] = fmaf(P, q0.y, z[1]);
            z[2] = fmaf(P, q0.z, z[2]);
            z[3] = fmaf(P, q0.w, z[3]);
            z[4] = fmaf(P, q1.x, z[4]);
            z[5] = fmaf(P, q1.y, z[5]);
            z[6] = fmaf(P, q1.z, z[6]);
            z[7] = fmaf(P, q1.w, z[7]);
            z[8] = fmaf(P, q2.x, z[8]);
            z[9] = fmaf(P, q2.y, z[9]);
        }
    }

    float2* po = (float2*)(out + bidx * NW);
    po[0] = make_float2(z[0], z[1]);
    po[1] = make_float2(z[2], z[3]);
    po[2] = make_float2(z[4], z[5]);
    po[3] = make_float2(z[6], z[7]);
    po[4] = make_float2(z[8], z[9]);
}

extern "C" void kernel_launch(void* const* d_in, const int* in_sizes, int n_in,
                              void* d_out, int out_size, void* d_ws, size_t ws_size,
                              hipStream_t stream) {
    const float* x     = (const float*)d_in[0];
    const float* theta = (const float*)d_in[1];
    float* out = (float*)d_out;
    float* Cg  = (float*)d_ws;          // 256*12*4 = 12288 B

    void* args[] = { (void*)&x, (void*)&theta, (void*)&out, (void*)&Cg };
    hipLaunchCooperativeKernel((void*)fused_all, dim3(128), dim3(128),
                               args, 0, stream);
}

// Round 5
// 81.961 us; speedup vs baseline: 1.3535x; 1.3535x over previous
//
#include <hip/hip_runtime.h>
#include <math.h>

#define BATCH 16384
#define NW 10
#define DEPTH 2

// ============================================================================
// Two regular kernels (cooperative launch regressed; multi-node gaps cost).
//  kA: 136 blocks x 64 threads. One wave per symmetric pair (a<=b) of encoded
//      basis states: simulate both batch-independent circuit columns u_a, u_b
//      in registers (verified shuffle simulator), reduce
//      C_w[a][b] = Re( i^(popc(a)-popc(b)) sum_i sign_w(i) conj(u_a_i) u_b_i )
//      and write both mirror slots (C real symmetric).
//  kB: 64 blocks x 256 threads. Transform C -> K (81 trig-basis terms x 10
//      wires) in LDS, then per-thread evaluate one batch element:
//      z_w(x) = sum_t K_w[t] * prod_q {1,cos x_q,sin x_q}_(t_q).
// ============================================================================

__device__ __forceinline__ void sim_column(int a, int lane,
                                           const float* ct, const float* st_,
                                           float re[16], float im[16])
{
#pragma unroll
    for (int r = 0; r < 16; ++r) { re[r] = 0.0f; im[r] = 0.0f; }
    if (lane == 0) re[a] = 1.0f;     // |a<<6>

#pragma unroll 1
    for (int d = 0; d < DEPTH; ++d) {
#pragma unroll
        for (int w = 0; w < 4; ++w) {            // RX on register wires
            const float c = ct[w], s = st_[w];
            const int m = 8 >> w;
#pragma unroll
            for (int r = 0; r < 16; ++r) {
                if (!(r & m)) {
                    const int r1 = r | m;
                    const float a0r = re[r],  a0i = im[r];
                    const float a1r = re[r1], a1i = im[r1];
                    re[r]  = c * a0r + s * a1i;
                    im[r]  = c * a0i - s * a1r;
                    re[r1] = c * a1r + s * a0i;
                    im[r1] = c * a1i - s * a0r;
                }
            }
        }
#pragma unroll
        for (int w = 4; w < 10; ++w) {           // RX on lane wires
            const float c = ct[w], s = st_[w];
            const int lm = 32 >> (w - 4);
#pragma unroll
            for (int r = 0; r < 16; ++r) {
                const float pr = __shfl_xor(re[r], lm, 64);
                const float pi = __shfl_xor(im[r], lm, 64);
                re[r] = c * re[r] + s * pi;
                im[r] = c * im[r] - s * pr;
            }
        }
        // ring CNOTs (0,1)(1,2)(2,3): register swaps
#pragma unroll
        for (int w = 0; w < 3; ++w) {
            const int cm = 8 >> w, tm = 8 >> (w + 1);
#pragma unroll
            for (int r = 0; r < 16; ++r) {
                if ((r & cm) && !(r & tm)) {
                    const int r2 = r | tm;
                    float t;
                    t = re[r]; re[r] = re[r2]; re[r2] = t;
                    t = im[r]; im[r] = im[r2]; im[r2] = t;
                }
            }
        }
        // (3,4): odd registers swap lanes across bit5
#pragma unroll
        for (int r = 0; r < 16; ++r) {
            if (r & 1) {
                re[r] = __shfl_xor(re[r], 32, 64);
                im[r] = __shfl_xor(im[r], 32, 64);
            }
        }
        // (4,5)..(8,9): lane-bit CNOTs
#pragma unroll
        for (int w = 4; w < 9; ++w) {
            const int cm = 32 >> (w - 4), tm = 32 >> (w - 3);
            const bool ctl = (lane & cm) != 0;
#pragma unroll
            for (int r = 0; r < 16; ++r) {
                const float pr = __shfl_xor(re[r], tm, 64);
                const float pi = __shfl_xor(im[r], tm, 64);
                re[r] = ctl ? pr : re[r];
                im[r] = ctl ? pi : im[r];
            }
        }
        // (9,0): lane-bit0 controlled register-bit3 swap
        {
            const bool ctl = (lane & 1) != 0;
#pragma unroll
            for (int r = 0; r < 8; ++r) {
                const float t0r = re[r], t1r = re[r + 8];
                const float t0i = im[r], t1i = im[r + 8];
                re[r]     = ctl ? t1r : t0r;
                re[r + 8] = ctl ? t0r : t1r;
                im[r]     = ctl ? t1i : t0i;
                im[r + 8] = ctl ? t0i : t1i;
            }
        }
    }
}

// ---- kernel A: one wave per symmetric pair -> C ------------------------
__global__ __launch_bounds__(64) void kA_pairs(const float* __restrict__ theta,
                                               float* __restrict__ Cg)
{
    const int lane = threadIdx.x;    // blockDim = 64, one wave

    // enumerate pair (a<=b) from block id (wave-uniform scalar loop)
    int t = blockIdx.x, a = 0;
    while (t >= 16 - a) { t -= 16 - a; ++a; }
    const int b = a + t;

    float ct[NW], st_[NW];
#pragma unroll
    for (int w = 0; w < NW; ++w) {
        const float h = 0.5f * theta[w];
        ct[w] = __cosf(h); st_[w] = __sinf(h);
    }

    float ar[16], ai[16], br[16], bi[16];
    sim_column(a, lane, ct, st_, ar, ai);
    if (b == a) {
#pragma unroll
        for (int r = 0; r < 16; ++r) { br[r] = ar[r]; bi[r] = ai[r]; }
    } else {
        sim_column(b, lane, ct, st_, br, bi);
    }

    const int p = (__popc(a) - __popc(b)) & 3;     // wave-uniform
    const bool odd = (p & 1) != 0;

    float red[10];
#pragma unroll
    for (int k = 0; k < 10; ++k) red[k] = 0.0f;
#pragma unroll
    for (int r = 0; r < 16; ++r) {
        const float vr = ar[r] * br[r] + ai[r] * bi[r];  // Re(conj(ua)*ub)
        const float vi = ar[r] * bi[r] - ai[r] * br[r];  // Im
        const float v  = odd ? vi : vr;
        red[0] += (r & 8) ? -v : v;     // wire 0 (reg bit 3)
        red[1] += (r & 4) ? -v : v;
        red[2] += (r & 2) ? -v : v;
        red[3] += (r & 1) ? -v : v;
        red[4] += v;
    }
    const float T = red[4];
    red[4] = (lane & 32) ? -T : T;      // wire 4 (lane bit 5)
    red[5] = (lane & 16) ? -T : T;
    red[6] = (lane &  8) ? -T : T;
    red[7] = (lane &  4) ? -T : T;
    red[8] = (lane &  2) ? -T : T;
    red[9] = (lane &  1) ? -T : T;

#pragma unroll
    for (int k = 0; k < 10; ++k) {
        float v = red[k];
#pragma unroll
        for (int ofs = 32; ofs >= 1; ofs >>= 1)
            v += __shfl_xor(v, ofs, 64);
        red[k] = v;
    }

    if (lane == 0) {
        // C = Re(i^p S): p=0 -> +Sr, 1 -> -Si, 2 -> -Sr, 3 -> +Si
        const float sg = (p == 1 || p == 2) ? -1.0f : 1.0f;
#pragma unroll
        for (int w = 0; w < NW; ++w) {
            const float val = sg * red[w];
            Cg[(a * 16 + b) * 12 + w] = val;
            Cg[(b * 16 + a) * 12 + w] = val;   // C symmetric
        }
    }
}

// ---- kernel B: C -> K in LDS, then per-batch evaluation ----------------
__global__ __launch_bounds__(256) void kB_eval(const float* __restrict__ x,
                                               const float* __restrict__ Cg,
                                               float* __restrict__ out)
{
    __shared__ float sC[256 * 12];
    __shared__ float sK[81 * 12];
    for (int i = threadIdx.x; i < 256 * 12; i += 256) sC[i] = Cg[i];
    __syncthreads();

    // K_w[t] = (1/16) sum over 16 signed C entries
    for (int idx = threadIdx.x; idx < 810; idx += 256) {
        const int t = idx / 10, w = idx - 10 * t;
        int d0 = t / 27, r0 = t - d0 * 27;
        int d1 = r0 / 9, r1 = r0 - d1 * 9;
        int d2 = r1 / 3, d3 = r1 - d2 * 3;
        const int d[4] = { d0, d1, d2, d3 };

        float s = 0.0f;
#pragma unroll
        for (int e = 0; e < 16; ++e) {
            int aa = 0, bb = 0; float sgn = 1.0f;
#pragma unroll
            for (int qq = 0; qq < 4; ++qq) {
                const int eq = (e >> (3 - qq)) & 1;
                int aq, bq;
                if (d[qq] == 2) { aq = eq; bq = 1 - eq; }
                else {
                    aq = eq; bq = eq;
                    if (d[qq] == 1 && eq) sgn = -sgn;
                }
                aa |= aq << (3 - qq);
                bb |= bq << (3 - qq);
            }
            s += sgn * sC[(aa * 16 + bb) * 12 + w];
        }
        sK[t * 12 + w] = s * 0.0625f;
    }
    __syncthreads();

    const int bidx = blockIdx.x * 256 + threadIdx.x;   // 0..16383
    const float4 xv = ((const float4*)x)[bidx];

    float s0, c0, s1, c1, s2, c2, s3, c3;
    __sincosf(xv.x, &s0, &c0);
    __sincosf(xv.y, &s1, &c1);
    __sincosf(xv.z, &s2, &c2);
    __sincosf(xv.w, &s3, &c3);

    const float b0[3] = { 1.0f, c0, s0 };
    const float b1[3] = { 1.0f, c1, s1 };
    const float b2[3] = { 1.0f, c2, s2 };
    const float b3[3] = { 1.0f, c3, s3 };
    float B01[9], B23[9];
#pragma unroll
    for (int i = 0; i < 3; ++i)
#pragma unroll
        for (int j = 0; j < 3; ++j) {
            B01[i * 3 + j] = b0[i] * b1[j];
            B23[i * 3 + j] = b2[i] * b3[j];
        }

    float z[NW];
#pragma unroll
    for (int w = 0; w < NW; ++w) z[w] = 0.0f;

#pragma unroll
    for (int t01 = 0; t01 < 9; ++t01) {
#pragma unroll
        for (int t23 = 0; t23 < 9; ++t23) {
            const float P = B01[t01] * B23[t23];
            const float* base = &sK[(t01 * 9 + t23) * 12];
            const float4 q0 = *(const float4*)(base + 0);
            const float4 q1 = *(const float4*)(base + 4);
            const float4 q2 = *(const float4*)(base + 8);
            z[0] = fmaf(P, q0.x, z[0]);
            z[1] = fmaf(P, q0.y, z[1]);
            z[2] = fmaf(P, q0.z, z[2]);
            z[3] = fmaf(P, q0.w, z[3]);
            z[4] = fmaf(P, q1.x, z[4]);
            z[5] = fmaf(P, q1.y, z[5]);
            z[6] = fmaf(P, q1.z, z[6]);
            z[7] = fmaf(P, q1.w, z[7]);
            z[8] = fmaf(P, q2.x, z[8]);
            z[9] = fmaf(P, q2.y, z[9]);
        }
    }

    float2* po = (float2*)(out + bidx * NW);
    po[0] = make_float2(z[0], z[1]);
    po[1] = make_float2(z[2], z[3]);
    po[2] = make_float2(z[4], z[5]);
    po[3] = make_float2(z[6], z[7]);
    po[4] = make_float2(z[8], z[9]);
}

extern "C" void kernel_launch(void* const* d_in, const int* in_sizes, int n_in,
                              void* d_out, int out_size, void* d_ws, size_t ws_size,
                              hipStream_t stream) {
    const float* x     = (const float*)d_in[0];
    const float* theta = (const float*)d_in[1];
    float* out = (float*)d_out;
    float* Cg  = (float*)d_ws;          // 256*12*4 = 12288 B

    hipLaunchKernelGGL(kA_pairs, dim3(136), dim3(64),  0, stream, theta, Cg);
    hipLaunchKernelGGL(kB_eval,  dim3(BATCH / 256), dim3(256), 0, stream, x, Cg, out);
}